// Round 5
// baseline (766.185 us; speedup 1.0000x reference)
//
#include <hip/hip_runtime.h>
#include <math.h>

#define N 8192
#define FIN 29
#define FH 8
#define NH 4
#define ALPHA 0.2f
#define LOG2E 1.4426950408889634f
#define JS 4            // layer-1 j-splits
#define JRR (N / JS)    // 2048

typedef unsigned long long ull;
typedef unsigned short u16;
typedef __attribute__((ext_vector_type(8))) short bf16x8;
typedef __attribute__((ext_vector_type(4))) float f32x4;
typedef __attribute__((ext_vector_type(2))) float f32x2;

__device__ inline unsigned bf16rn(float f) {
    unsigned u = __float_as_uint(f);
    return (u + 0x7fffu + ((u >> 16) & 1u)) >> 16;
}
// packed f32 pair multiply (VOP3P) — one instruction, two products
__device__ inline f32x2 pk_mul(f32x2 a, f32x2 b) {
    f32x2 d;
    asm("v_pk_mul_f32 %0, %1, %2" : "=v"(d) : "v"(a), "v"(b));
    return d;
}

// w_ij = exp2(lrelu(f1+f2) - m) = max(E1p_i*E2p_j, E1n_i*E2n_j)  (exp2 monotone)
#define WTILE(E1P2, E1N2, SW, ACC)                                              \
    {                                                                           \
        f32x2 wp, wn;                                                           \
        float w0, w1, w2, w3, w4, w5, w6, w7;                                   \
        wp = pk_mul(E1P2, p01); wn = pk_mul(E1N2, n01);                         \
        w0 = fmaxf(wp[0], wn[0]); w1 = fmaxf(wp[1], wn[1]);                     \
        wp = pk_mul(E1P2, p23); wn = pk_mul(E1N2, n23);                         \
        w2 = fmaxf(wp[0], wn[0]); w3 = fmaxf(wp[1], wn[1]);                     \
        wp = pk_mul(E1P2, p45); wn = pk_mul(E1N2, n45);                         \
        w4 = fmaxf(wp[0], wn[0]); w5 = fmaxf(wp[1], wn[1]);                     \
        wp = pk_mul(E1P2, p67); wn = pk_mul(E1N2, n67);                         \
        w6 = fmaxf(wp[0], wn[0]); w7 = fmaxf(wp[1], wn[1]);                     \
        w0 = (SW & 1u)   ? w0 : 0.f;                                            \
        w1 = (SW & 2u)   ? w1 : 0.f;                                            \
        w2 = (SW & 4u)   ? w2 : 0.f;                                            \
        w3 = (SW & 8u)   ? w3 : 0.f;                                            \
        w4 = (SW & 16u)  ? w4 : 0.f;                                            \
        w5 = (SW & 32u)  ? w5 : 0.f;                                            \
        w6 = (SW & 64u)  ? w6 : 0.f;                                            \
        w7 = (SW & 128u) ? w7 : 0.f;                                            \
        uint4 ap;                                                               \
        asm("v_cvt_pk_bf16_f32 %0, %1, %2" : "=v"(ap.x) : "v"(w0), "v"(w1));    \
        asm("v_cvt_pk_bf16_f32 %0, %1, %2" : "=v"(ap.y) : "v"(w2), "v"(w3));    \
        asm("v_cvt_pk_bf16_f32 %0, %1, %2" : "=v"(ap.z) : "v"(w4), "v"(w5));    \
        asm("v_cvt_pk_bf16_f32 %0, %1, %2" : "=v"(ap.w) : "v"(w6), "v"(w7));    \
        ACC = __builtin_amdgcn_mfma_f32_16x16x32_bf16(                          \
            __builtin_bit_cast(bf16x8, ap), __builtin_bit_cast(bf16x8, bp),     \
            ACC, 0, 0, 0);                                                      \
    }

// ============ Kernel A: adj pack (direct-transposed) + per-node features ============
// 1024 blocks x 256 thr, 8 rows/nodes per block.
// maskT[w][row] bit lane <-> adj[row][w*64+lane]  (word w = i*4+wv, col i*256+tid)
// Features (32 threads): f1a, e2p/e2n (exp factors), Bpk (MFMA fragment order,
// c=8 -> ones column for the free denominator), bmax1[h][blk] per-block f2 max.
// No atomics anywhere -> no poisoned-init hazards.
__global__ void kA_pack_feat(
    const int* __restrict__ adj, const float* __restrict__ x,
    const float* __restrict__ Wh, const float* __restrict__ ah,
    ull* __restrict__ maskT, float* __restrict__ e2p, float* __restrict__ e2n,
    u16* __restrict__ Bpk, float* __restrict__ f1a, float* __restrict__ bmax1) {
    __shared__ float sW[NH * FIN * FH];
    __shared__ float sa[NH * 2 * FH];
    const int tid = threadIdx.x;
    const int blk = blockIdx.x;
    const int lane = tid & 63;
    const int wv = tid >> 6;
    for (int i = tid; i < NH * FIN * FH; i += 256) sW[i] = Wh[i];
    for (int i = tid; i < NH * 2 * FH; i += 256) sa[i] = ah[i];
    __syncthreads();
    if (tid < 32) {           // 8 nodes x 4 heads
        int nl = tid >> 2, h = tid & 3;
        int node = blk * 8 + nl;
        float xr[FIN];
#pragma unroll
        for (int f = 0; f < FIN; f++) xr[f] = x[node * FIN + f];
        float hv[FH];
#pragma unroll
        for (int k = 0; k < FH; k++) {
            float s = 0.f;
#pragma unroll
            for (int f = 0; f < FIN; f++) s += xr[f] * sW[(h * FIN + f) * FH + k];
            hv[k] = s;
        }
        float f1 = 0.f, f2 = 0.f;
#pragma unroll
        for (int k = 0; k < FH; k++) {
            f1 += hv[k] * sa[h * 16 + k];
            f2 += hv[k] * sa[h * 16 + 8 + k];
        }
        float f1L = f1 * LOG2E, f2L = f2 * LOG2E;
        f1a[node * 4 + h] = f1L;
        e2p[h * N + node] = __builtin_amdgcn_exp2f(f2L);
        e2n[h * N + node] = __builtin_amdgcn_exp2f(ALPHA * f2L);
        // MFMA-fragment-order pack
        int js = node >> 11;
        int t = (node >> 6) & 31;
        int hfl = (node >> 5) & 1;
        int kb = (node >> 3) & 3;
        int e = node & 7;
        u16* dst = Bpk + ((size_t)(((h * 4 + js) * 32 + t) * 2 + hfl)) * 512 + e;
#pragma unroll
        for (int cc = 0; cc < 16; cc++) {
            u16 vv = (cc < FH) ? (u16)bf16rn(hv[cc])
                               : ((cc == 8) ? (u16)0x3F80u : (u16)0);
            dst[(kb * 16 + cc) * 8] = vv;
        }
        // per-head max over this block's 8 nodes (head classes = lane mod 4)
        float v = f2L;
        for (int off = 4; off < 32; off <<= 1) v = fmaxf(v, __shfl_xor(v, off, 64));
        if (tid < 4) bmax1[tid * 1024 + blk] = v;
    }
    // pack 8 rows of adj, writing the transposed bitmask directly
    for (int rr = 0; rr < 8; rr++) {
        const int* rp = adj + (size_t)(blk * 8 + rr) * N;
#pragma unroll 8
        for (int i = 0; i < 32; i++) {
            int a = rp[i * 256 + tid];
            ull b = __ballot(a > 0);
            if (lane == 0) maskT[(size_t)(i * 4 + wv) * N + blk * 8 + rr] = b;
        }
    }
}

// ============ Kernel B: layer-1 attention via MFMA (round-3 proven body) ============
// IDEMPOTENT: reads only A's outputs, writes only part1 (deterministic).
__global__ __launch_bounds__(256, 4) void kB_attn1(
    const ull* __restrict__ maskT, const float* __restrict__ e2p,
    const float* __restrict__ e2n, const uint4* __restrict__ Bpk,
    const float* __restrict__ f1a, const float* __restrict__ bmax1,
    float* __restrict__ part1) {
    __shared__ float sred[4];
    int tid = threadIdx.x;
    int lane = tid & 63;
    int wv = tid >> 6;
    int h = blockIdx.x & 3;
    int js = (blockIdx.x >> 2) & 3;
    int rowblk = blockIdx.x >> 4;        // 0..63
    int jbase = js * JRR;

    // mfL = global max of f2L for this head (reduce bmax1[h][0..1023])
    float v = -3.0e38f;
    for (int i = tid; i < 1024; i += 256) v = fmaxf(v, bmax1[h * 1024 + i]);
    for (int off = 32; off > 0; off >>= 1) v = fmaxf(v, __shfl_xor(v, off, 64));
    if (lane == 0) sred[wv] = v;
    __syncthreads();
    float mfL = fmaxf(fmaxf(sred[0], sred[1]), fmaxf(sred[2], sred[3]));

    int c = lane & 15;                   // B col / A row selector
    int kb = lane >> 4;                  // k-group 0..3
    int sh = kb * 8;
    int r0 = rowblk * 128 + wv * 16 + c;
    int r1 = r0 + 64;

    float f1 = f1a[r0 * 4 + h];
    float vv = f1 + mfL, mm = fmaxf(vv, ALPHA * vv);
    f32x2 e1p0, e1n0, e1p1, e1n1;
    e1p0[0] = e1p0[1] = __builtin_amdgcn_exp2f(f1 - mm);
    e1n0[0] = e1n0[1] = __builtin_amdgcn_exp2f(ALPHA * f1 - mm);
    f1 = f1a[r1 * 4 + h];
    vv = f1 + mfL; mm = fmaxf(vv, ALPHA * vv);
    e1p1[0] = e1p1[1] = __builtin_amdgcn_exp2f(f1 - mm);
    e1n1[0] = e1n1[1] = __builtin_amdgcn_exp2f(ALPHA * f1 - mm);

    const ull* mT = maskT + (size_t)(jbase >> 6) * N;
    const float* pph = e2p + (size_t)h * N + jbase + kb * 8;
    const float* nnh = e2n + (size_t)h * N + jbase + kb * 8;
    const uint4* bp0 = Bpk + (size_t)(h * 4 + js) * 4096 + lane;

    f32x4 acc0 = {0.f, 0.f, 0.f, 0.f};
    f32x4 acc1 = {0.f, 0.f, 0.f, 0.f};

    for (int t = 0; t < JRR / 64; t++) {   // 32
        ull mw0 = mT[(size_t)t * N + r0];
        ull mw1 = mT[(size_t)t * N + r1];
#pragma unroll
        for (int hf = 0; hf < 2; hf++) {
            f32x4 P0 = *(const f32x4*)(pph + t * 64 + hf * 32);
            f32x4 P1 = *(const f32x4*)(pph + t * 64 + hf * 32 + 4);
            f32x4 Q0 = *(const f32x4*)(nnh + t * 64 + hf * 32);
            f32x4 Q1 = *(const f32x4*)(nnh + t * 64 + hf * 32 + 4);
            f32x2 p01 = __builtin_shufflevector(P0, P0, 0, 1);
            f32x2 p23 = __builtin_shufflevector(P0, P0, 2, 3);
            f32x2 p45 = __builtin_shufflevector(P1, P1, 0, 1);
            f32x2 p67 = __builtin_shufflevector(P1, P1, 2, 3);
            f32x2 n01 = __builtin_shufflevector(Q0, Q0, 0, 1);
            f32x2 n23 = __builtin_shufflevector(Q0, Q0, 2, 3);
            f32x2 n45 = __builtin_shufflevector(Q1, Q1, 0, 1);
            f32x2 n67 = __builtin_shufflevector(Q1, Q1, 2, 3);
            uint4 bp = bp0[(t * 2 + hf) * 64];
            unsigned sw0 = ((unsigned)(mw0 >> (hf * 32))) >> sh;
            unsigned sw1 = ((unsigned)(mw1 >> (hf * 32))) >> sh;
            WTILE(e1p0, e1n0, sw0, acc0)
            WTILE(e1p1, e1n1, sw1, acc1)
        }
    }
    if (c <= 8) {   // cols 0..7 = features, 8 = denominator
        int ro = rowblk * 128 + wv * 16 + kb * 4;
        float* dstp = part1 + (size_t)(js * 36 + h * 9 + c) * N + ro;
        *(float4*)dstp = make_float4(acc0[0], acc0[1], acc0[2], acc0[3]);
        *(float4*)(dstp + 64) = make_float4(acc1[0], acc1[1], acc1[2], acc1[3]);
    }
}

// ============ Kernel C: finalize layer 1 + layer-2 features + bmax2 ============
__global__ void kC_final1(const float* __restrict__ part1, const float* __restrict__ Wo,
                          const float* __restrict__ ao,
                          float4* __restrict__ rec2, float* __restrict__ f1b,
                          float* __restrict__ bmax2) {
    __shared__ float sW[64];
    __shared__ float sa[4];
    __shared__ float sred[4];
    int tid = threadIdx.x;
    if (tid < 64) sW[tid] = Wo[tid];
    if (tid < 4) sa[tid] = ao[tid];
    __syncthreads();
    int row = blockIdx.x * 256 + tid;
    float hv[32];
#pragma unroll
    for (int h = 0; h < NH; h++) {
        float s[9];
#pragma unroll
        for (int cc = 0; cc < 9; cc++) {
            float acc = 0.f;
#pragma unroll
            for (int js = 0; js < JS; js++)
                acc += part1[(size_t)(js * 36 + h * 9 + cc) * N + row];
            s[cc] = acc;
        }
        float inv = 1.f / s[8];
#pragma unroll
        for (int k = 0; k < FH; k++) {
            float o = s[k] * inv;
            hv[h * 8 + k] = (o > 0.f) ? o : expm1f(o);
        }
    }
    float h0 = 0.f, h1 = 0.f;
#pragma unroll
    for (int i = 0; i < 32; i++) {
        h0 = fmaf(hv[i], sW[i * 2 + 0], h0);
        h1 = fmaf(hv[i], sW[i * 2 + 1], h1);
    }
    float f1 = (h0 * sa[0] + h1 * sa[1]) * LOG2E;
    float f2 = (h0 * sa[2] + h1 * sa[3]) * LOG2E;
    rec2[row] = make_float4(__builtin_amdgcn_exp2f(f2), h0, h1,
                            __builtin_amdgcn_exp2f(ALPHA * f2));
    f1b[row] = f1;
    float vmax = f2;
    for (int off = 32; off > 0; off >>= 1) vmax = fmaxf(vmax, __shfl_xor(vmax, off, 64));
    if ((tid & 63) == 0) sred[tid >> 6] = vmax;
    __syncthreads();
    if (tid == 0)
        bmax2[blockIdx.x] = fmaxf(fmaxf(sred[0], sred[1]), fmaxf(sred[2], sred[3]));
}

// ============ Kernel D: layer-2 attention + log_softmax (fused) ============
__global__ __launch_bounds__(256) void kD_attn2(
    const ull* __restrict__ maskT, const float4* __restrict__ rec2,
    const float* __restrict__ f1b, const float* __restrict__ bmax2,
    float* __restrict__ out) {
    __shared__ float sred[4];
    int tid = threadIdx.x;
    int lane = tid & 63;
    int wv = tid >> 6;

    // mb = global max of layer-2 f2 (reduce bmax2[0..31])
    float v = (tid < 32) ? bmax2[tid] : -3.0e38f;
    for (int off = 32; off > 0; off >>= 1) v = fmaxf(v, __shfl_xor(v, off, 64));
    if (lane == 0) sred[wv] = v;
    __syncthreads();
    float mb = fmaxf(fmaxf(sred[0], sred[1]), fmaxf(sred[2], sred[3]));

    int r0 = blockIdx.x * 8 + wv * 2;   // rows r0, r0+1
    float f1 = f1b[r0];
    float vv = f1 + mb, mm = fmaxf(vv, ALPHA * vv);
    float q1p0 = __builtin_amdgcn_exp2f(f1 - mm);
    float q1n0 = __builtin_amdgcn_exp2f(ALPHA * f1 - mm);
    f1 = f1b[r0 + 1];
    vv = f1 + mb; mm = fmaxf(vv, ALPHA * vv);
    float q1p1 = __builtin_amdgcn_exp2f(f1 - mm);
    float q1n1 = __builtin_amdgcn_exp2f(ALPHA * f1 - mm);

    float a00 = 0.f, a10 = 0.f, d0 = 0.f;
    float a01 = 0.f, a11 = 0.f, d1 = 0.f;
#pragma unroll 4
    for (int s = 0; s < N / 64; s++) {   // 128
        float4 q = rec2[s * 64 + lane];
        ull mw0 = maskT[(size_t)s * N + r0];
        ull mw1 = maskT[(size_t)s * N + r0 + 1];
        float w0 = fmaxf(q1p0 * q.x, q1n0 * q.w);
        w0 = ((mw0 >> lane) & 1ull) ? w0 : 0.f;
        float w1 = fmaxf(q1p1 * q.x, q1n1 * q.w);
        w1 = ((mw1 >> lane) & 1ull) ? w1 : 0.f;
        a00 = fmaf(w0, q.y, a00);
        a10 = fmaf(w0, q.z, a10);
        d0 += w0;
        a01 = fmaf(w1, q.y, a01);
        a11 = fmaf(w1, q.z, a11);
        d1 += w1;
    }
    for (int off = 32; off > 0; off >>= 1) {
        a00 += __shfl_xor(a00, off, 64);
        a10 += __shfl_xor(a10, off, 64);
        d0  += __shfl_xor(d0,  off, 64);
        a01 += __shfl_xor(a01, off, 64);
        a11 += __shfl_xor(a11, off, 64);
        d1  += __shfl_xor(d1,  off, 64);
    }
    if (lane == 0) {
#pragma unroll
        for (int i = 0; i < 2; i++) {
            float s0 = i ? a01 : a00;
            float s1 = i ? a11 : a10;
            float dd = i ? d1 : d0;
            float iv = 1.f / dd;
            float e0 = s0 * iv, e1 = s1 * iv;
            e0 = (e0 > 0.f) ? e0 : expm1f(e0);
            e1 = (e1 > 0.f) ? e1 : expm1f(e1);
            float mx = fmaxf(e0, e1);
            float lse = mx + logf(expf(e0 - mx) + expf(e1 - mx));
            ((float2*)out)[r0 + i] = make_float2(e0 - lse, e1 - lse);
        }
    }
}

extern "C" void kernel_launch(void* const* d_in, const int* in_sizes, int n_in,
                              void* d_out, int out_size, void* d_ws, size_t ws_size,
                              hipStream_t stream) {
    const float* x   = (const float*)d_in[0];
    const int*   adj = (const int*)d_in[1];
    const float* Wh  = (const float*)d_in[2];
    const float* ah  = (const float*)d_in[3];
    const float* Wo  = (const float*)d_in[4];
    const float* ao  = (const float*)d_in[5];
    float* out = (float*)d_out;
    float* ws = (float*)d_ws;

    // workspace layout (float offsets)
    ull*    maskT = (ull*)ws;                    // 8 MB word-transposed bitmask
    float*  e2p   = ws + 2097152;                // 4*N
    float*  e2n   = ws + 2129920;                // 4*N
    u16*    Bpk   = (u16*)(ws + 2162688);        // 1 MB
    float*  f1a   = ws + 2424832;                // 4*N
    float*  part1 = ws + 2457600;                // 4*36*N = 1179648
    float4* rec2  = (float4*)(ws + 3637248);     // N float4
    float*  f1b   = ws + 3670016;                // N
    float*  bmax1 = ws + 3678208;                // 4*1024
    float*  bmax2 = ws + 3682304;                // 32

    kA_pack_feat<<<1024, 256, 0, stream>>>(adj, x, Wh, ah, maskT, e2p, e2n, Bpk,
                                           f1a, bmax1);
    // B launched 3x ON PURPOSE (idempotent): dur delta = 2*T(B) pins the
    // hidden kernel time that rounds 1-3 could not see below the fill cutoff.
    kB_attn1<<<1024, 256, 0, stream>>>(maskT, e2p, e2n, (const uint4*)Bpk, f1a,
                                       bmax1, part1);
    kB_attn1<<<1024, 256, 0, stream>>>(maskT, e2p, e2n, (const uint4*)Bpk, f1a,
                                       bmax1, part1);
    kB_attn1<<<1024, 256, 0, stream>>>(maskT, e2p, e2n, (const uint4*)Bpk, f1a,
                                       bmax1, part1);
    kC_final1<<<32, 256, 0, stream>>>(part1, Wo, ao, rec2, f1b, bmax2);
    kD_attn2<<<1024, 256, 0, stream>>>(maskT, rec2, f1b, bmax2, out);
}

// Round 6
// 534.467 us; speedup vs baseline: 1.4335x; 1.4335x over previous
//
#include <hip/hip_runtime.h>
#include <math.h>

#define N 8192
#define FIN 29
#define FH 8
#define NH 4
#define ALPHA 0.2f
#define LOG2E 1.4426950408889634f
#define JS 8            // layer-1 j-splits (8 -> 2048 blocks = 8/CU occupancy)
#define JRR (N / JS)    // 1024

typedef unsigned long long ull;
typedef unsigned short u16;
typedef __attribute__((ext_vector_type(8))) short bf16x8;
typedef __attribute__((ext_vector_type(4))) float f32x4;
typedef __attribute__((ext_vector_type(2))) float f32x2;

__device__ inline unsigned bf16rn(float f) {
    unsigned u = __float_as_uint(f);
    return (u + 0x7fffu + ((u >> 16) & 1u)) >> 16;
}
// packed f32 pair multiply (VOP3P) — one instruction, two products
__device__ inline f32x2 pk_mul(f32x2 a, f32x2 b) {
    f32x2 d;
    asm("v_pk_mul_f32 %0, %1, %2" : "=v"(d) : "v"(a), "v"(b));
    return d;
}

// w_ij = exp2(lrelu(f1+f2) - m) = max(E1p_i*E2p_j, E1n_i*E2n_j)  (exp2 monotone)
#define WTILE(E1P2, E1N2, SW, ACC)                                              \
    {                                                                           \
        f32x2 wp, wn;                                                           \
        float w0, w1, w2, w3, w4, w5, w6, w7;                                   \
        wp = pk_mul(E1P2, p01); wn = pk_mul(E1N2, n01);                         \
        w0 = fmaxf(wp[0], wn[0]); w1 = fmaxf(wp[1], wn[1]);                     \
        wp = pk_mul(E1P2, p23); wn = pk_mul(E1N2, n23);                         \
        w2 = fmaxf(wp[0], wn[0]); w3 = fmaxf(wp[1], wn[1]);                     \
        wp = pk_mul(E1P2, p45); wn = pk_mul(E1N2, n45);                         \
        w4 = fmaxf(wp[0], wn[0]); w5 = fmaxf(wp[1], wn[1]);                     \
        wp = pk_mul(E1P2, p67); wn = pk_mul(E1N2, n67);                         \
        w6 = fmaxf(wp[0], wn[0]); w7 = fmaxf(wp[1], wn[1]);                     \
        w0 = (SW & 1u)   ? w0 : 0.f;                                            \
        w1 = (SW & 2u)   ? w1 : 0.f;                                            \
        w2 = (SW & 4u)   ? w2 : 0.f;                                            \
        w3 = (SW & 8u)   ? w3 : 0.f;                                            \
        w4 = (SW & 16u)  ? w4 : 0.f;                                            \
        w5 = (SW & 32u)  ? w5 : 0.f;                                            \
        w6 = (SW & 64u)  ? w6 : 0.f;                                            \
        w7 = (SW & 128u) ? w7 : 0.f;                                            \
        uint4 ap;                                                               \
        asm("v_cvt_pk_bf16_f32 %0, %1, %2" : "=v"(ap.x) : "v"(w0), "v"(w1));    \
        asm("v_cvt_pk_bf16_f32 %0, %1, %2" : "=v"(ap.y) : "v"(w2), "v"(w3));    \
        asm("v_cvt_pk_bf16_f32 %0, %1, %2" : "=v"(ap.z) : "v"(w4), "v"(w5));    \
        asm("v_cvt_pk_bf16_f32 %0, %1, %2" : "=v"(ap.w) : "v"(w6), "v"(w7));    \
        ACC = __builtin_amdgcn_mfma_f32_16x16x32_bf16(                          \
            __builtin_bit_cast(bf16x8, ap), __builtin_bit_cast(bf16x8, bp),     \
            ACC, 0, 0, 0);                                                      \
    }

// ============ kPack: adj (256 MB) -> transposed bitmask maskT[word][row] ============
// 8192 blocks x 256 thr, ONE row per block (round-3-proven parallelism: 32
// blocks/CU, latency fully hidden). Transposed store direct (no k0t pass).
// bit of word w=(i*4+wv), lane <-> element i*256 + wv*64 + lane = i*256+tid.
__global__ void kPack(const int* __restrict__ adj, ull* __restrict__ maskT) {
    int row = blockIdx.x;
    int tid = threadIdx.x;
    int lane = tid & 63;
    int wv = tid >> 6;
    const int* rp = adj + (size_t)row * N;
#pragma unroll 8
    for (int i = 0; i < 32; i++) {
        int a = rp[i * 256 + tid];
        ull b = __ballot(a > 0);
        if (lane == 0) maskT[(size_t)(i * 4 + wv) * N + row] = b;
    }
}

// ============ kFeat: per-node features, one thread per (node, head) ============
// e2p/e2n = per-column exp factors; Bpk = MFMA B operand in fragment order
// (c=8 -> ones column gives the softmax denominator for free);
// f1a = per-row logit; bmax1[h][blk*4+wv] = per-wave f2 max (no atomics).
__global__ __launch_bounds__(256) void kFeat(
    const float* __restrict__ x, const float* __restrict__ Wh,
    const float* __restrict__ ah,
    float* __restrict__ e2p, float* __restrict__ e2n, u16* __restrict__ Bpk,
    float* __restrict__ f1a, float* __restrict__ bmax1) {
    __shared__ float sx[64 * FIN];
    __shared__ float sW[NH * FIN * FH];
    __shared__ float sa[NH * 2 * FH];
    int tid = threadIdx.x;
    int wv = tid >> 6;
    for (int i = tid; i < NH * FIN * FH; i += 256) sW[i] = Wh[i];
    for (int i = tid; i < NH * 2 * FH; i += 256) sa[i] = ah[i];
    for (int i = tid; i < 64 * FIN; i += 256) sx[i] = x[(size_t)blockIdx.x * 64 * FIN + i];
    __syncthreads();
    int h = tid & 3;
    int nl = tid >> 2;                  // node-local 0..63
    int node = blockIdx.x * 64 + nl;
    float hv[FH];
#pragma unroll
    for (int k = 0; k < FH; k++) {
        float s = 0.f;
#pragma unroll
        for (int f = 0; f < FIN; f++) s += sx[nl * FIN + f] * sW[(h * FIN + f) * FH + k];
        hv[k] = s;
    }
    float f1 = 0.f, f2 = 0.f;
#pragma unroll
    for (int k = 0; k < FH; k++) {
        f1 += hv[k] * sa[h * 16 + k];
        f2 += hv[k] * sa[h * 16 + 8 + k];
    }
    float f1L = f1 * LOG2E, f2L = f2 * LOG2E;
    f1a[node * 4 + h] = f1L;
    e2p[(size_t)h * N + node] = __builtin_amdgcn_exp2f(f2L);
    e2n[(size_t)h * N + node] = __builtin_amdgcn_exp2f(ALPHA * f2L);
    // MFMA-fragment-order pack (JS=8 decomposition)
    int js = (node >> 10) & 7;
    int t  = (node >> 6) & 15;
    int hfl = (node >> 5) & 1;
    int kb = (node >> 3) & 3;
    int e  = node & 7;
    u16* dst = Bpk + ((size_t)(((h * 8 + js) * 16 + t) * 2 + hfl)) * 512 + e;
#pragma unroll
    for (int cc = 0; cc < 16; cc++) {
        u16 vv = (cc < FH) ? (u16)bf16rn(hv[cc])
                           : ((cc == 8) ? (u16)0x3F80u : (u16)0);
        dst[(kb * 16 + cc) * 8] = vv;
    }
    // per-head max over this wave's 16 nodes (head classes = lane mod 4)
    float v = f2L;
    for (int off = 4; off < 64; off <<= 1) v = fmaxf(v, __shfl_xor(v, off, 64));
    if ((tid & 63) < 4) bmax1[(tid & 3) * 512 + blockIdx.x * 4 + wv] = v;
}

// ============ kB: layer-1 attention via MFMA ============
// Grid 2048 (8 blocks/CU), LDS-staged e2 slabs (VMEM per iter: mask + Bpk only).
// Each wave owns TWO 16-row tiles sharing B fragment + e2 reads.
__global__ __launch_bounds__(256, 6) void kB_attn1(
    const ull* __restrict__ maskT, const float* __restrict__ e2p,
    const float* __restrict__ e2n, const uint4* __restrict__ Bpk,
    const float* __restrict__ f1a, const float* __restrict__ bmax1,
    float* __restrict__ part1) {
    __shared__ __align__(16) float sE2p[JRR];   // 4 KB
    __shared__ __align__(16) float sE2n[JRR];   // 4 KB
    __shared__ float sred[4];
    int tid = threadIdx.x;
    int lane = tid & 63;
    int wv = tid >> 6;
    int h = blockIdx.x & 3;
    int js = (blockIdx.x >> 2) & 7;
    int rowblk = blockIdx.x >> 5;        // 0..63
    int jbase = js * JRR;

    // stage e2 slabs for this (head, j-range)
#pragma unroll
    for (int i = 0; i < JRR / 256; i++) {   // 4
        sE2p[tid + i * 256] = e2p[(size_t)h * N + jbase + tid + i * 256];
        sE2n[tid + i * 256] = e2n[(size_t)h * N + jbase + tid + i * 256];
    }
    // mfL = global max of f2L for this head (reduce bmax1[h][0..511])
    float v = -3.0e38f;
    for (int i = tid; i < 512; i += 256) v = fmaxf(v, bmax1[h * 512 + i]);
    for (int off = 32; off > 0; off >>= 1) v = fmaxf(v, __shfl_xor(v, off, 64));
    if (lane == 0) sred[wv] = v;
    __syncthreads();
    float mfL = fmaxf(fmaxf(sred[0], sred[1]), fmaxf(sred[2], sred[3]));

    int c = lane & 15;                   // B col / A row selector
    int kb = lane >> 4;                  // k-group 0..3
    int sh = kb * 8;
    int r0 = rowblk * 128 + wv * 16 + c;
    int r1 = r0 + 64;

    float f1 = f1a[r0 * 4 + h];
    float vv = f1 + mfL, mm = fmaxf(vv, ALPHA * vv);
    f32x2 e1p0, e1n0, e1p1, e1n1;
    e1p0[0] = e1p0[1] = __builtin_amdgcn_exp2f(f1 - mm);
    e1n0[0] = e1n0[1] = __builtin_amdgcn_exp2f(ALPHA * f1 - mm);
    f1 = f1a[r1 * 4 + h];
    vv = f1 + mfL; mm = fmaxf(vv, ALPHA * vv);
    e1p1[0] = e1p1[1] = __builtin_amdgcn_exp2f(f1 - mm);
    e1n1[0] = e1n1[1] = __builtin_amdgcn_exp2f(ALPHA * f1 - mm);

    const ull* mT = maskT + (size_t)(js * (JRR / 64)) * N;
    const uint4* bp0 = Bpk + (size_t)(h * 8 + js) * 2048 + lane;
    const float* pph = sE2p + kb * 8;
    const float* nnh = sE2n + kb * 8;

    f32x4 acc0 = {0.f, 0.f, 0.f, 0.f};
    f32x4 acc1 = {0.f, 0.f, 0.f, 0.f};

    for (int t = 0; t < JRR / 64; t++) {   // 16
        ull mw0 = mT[(size_t)t * N + r0];   // 128 B contiguous per 16-lane group
        ull mw1 = mT[(size_t)t * N + r1];
#pragma unroll
        for (int hf = 0; hf < 2; hf++) {
            f32x4 P0 = *(const f32x4*)(pph + t * 64 + hf * 32);
            f32x4 P1 = *(const f32x4*)(pph + t * 64 + hf * 32 + 4);
            f32x4 Q0 = *(const f32x4*)(nnh + t * 64 + hf * 32);
            f32x4 Q1 = *(const f32x4*)(nnh + t * 64 + hf * 32 + 4);
            f32x2 p01 = __builtin_shufflevector(P0, P0, 0, 1);
            f32x2 p23 = __builtin_shufflevector(P0, P0, 2, 3);
            f32x2 p45 = __builtin_shufflevector(P1, P1, 0, 1);
            f32x2 p67 = __builtin_shufflevector(P1, P1, 2, 3);
            f32x2 n01 = __builtin_shufflevector(Q0, Q0, 0, 1);
            f32x2 n23 = __builtin_shufflevector(Q0, Q0, 2, 3);
            f32x2 n45 = __builtin_shufflevector(Q1, Q1, 0, 1);
            f32x2 n67 = __builtin_shufflevector(Q1, Q1, 2, 3);
            uint4 bp = bp0[(t * 2 + hf) * 64];
            unsigned sw0 = ((unsigned)(mw0 >> (hf * 32))) >> sh;
            unsigned sw1 = ((unsigned)(mw1 >> (hf * 32))) >> sh;
            WTILE(e1p0, e1n0, sw0, acc0)
            WTILE(e1p1, e1n1, sw1, acc1)
        }
    }
    if (c <= 8) {   // cols 0..7 = features, 8 = denominator
        int ro = rowblk * 128 + wv * 16 + kb * 4;
        float* dstp = part1 + (size_t)(js * 36 + h * 9 + c) * N + ro;
        *(float4*)dstp = make_float4(acc0[0], acc0[1], acc0[2], acc0[3]);
        *(float4*)(dstp + 64) = make_float4(acc1[0], acc1[1], acc1[2], acc1[3]);
    }
}

// ============ kC: finalize layer 1 + layer-2 features + bmax2 ============
// 128 blocks x 64 thr (one wave), one row per thread.
__global__ __launch_bounds__(64) void kC_final1(
    const float* __restrict__ part1, const float* __restrict__ Wo,
    const float* __restrict__ ao,
    float4* __restrict__ rec2, float* __restrict__ f1b,
    float* __restrict__ bmax2) {
    __shared__ float sW[64];
    __shared__ float sa[4];
    int tid = threadIdx.x;
    sW[tid] = Wo[tid];
    if (tid < 4) sa[tid] = ao[tid];
    __syncthreads();
    int row = blockIdx.x * 64 + tid;
    float hv[32];
#pragma unroll
    for (int h = 0; h < NH; h++) {
        float s[9];
#pragma unroll
        for (int cc = 0; cc < 9; cc++) {
            float acc = 0.f;
#pragma unroll
            for (int js = 0; js < JS; js++)
                acc += part1[(size_t)(js * 36 + h * 9 + cc) * N + row];
            s[cc] = acc;
        }
        float inv = 1.f / s[8];
#pragma unroll
        for (int k = 0; k < FH; k++) {
            float o = s[k] * inv;
            hv[h * 8 + k] = (o > 0.f) ? o : expm1f(o);
        }
    }
    float h0 = 0.f, h1 = 0.f;
#pragma unroll
    for (int i = 0; i < 32; i++) {
        h0 = fmaf(hv[i], sW[i * 2 + 0], h0);
        h1 = fmaf(hv[i], sW[i * 2 + 1], h1);
    }
    float f1 = (h0 * sa[0] + h1 * sa[1]) * LOG2E;
    float f2 = (h0 * sa[2] + h1 * sa[3]) * LOG2E;
    rec2[row] = make_float4(__builtin_amdgcn_exp2f(f2), h0, h1,
                            __builtin_amdgcn_exp2f(ALPHA * f2));
    f1b[row] = f1;
    float vmax = f2;
    for (int off = 32; off > 0; off >>= 1) vmax = fmaxf(vmax, __shfl_xor(vmax, off, 64));
    if (tid == 0) bmax2[blockIdx.x] = vmax;
}

// ============ kD: layer-2 attention + log_softmax (fused) ============
__global__ __launch_bounds__(256) void kD_attn2(
    const ull* __restrict__ maskT, const float4* __restrict__ rec2,
    const float* __restrict__ f1b, const float* __restrict__ bmax2,
    float* __restrict__ out) {
    __shared__ float sred[4];
    int tid = threadIdx.x;
    int lane = tid & 63;
    int wv = tid >> 6;

    // mb = global max of layer-2 f2 (reduce bmax2[0..127])
    float v = (tid < 128) ? bmax2[tid] : -3.0e38f;
    for (int off = 32; off > 0; off >>= 1) v = fmaxf(v, __shfl_xor(v, off, 64));
    if (lane == 0) sred[wv] = v;
    __syncthreads();
    float mb = fmaxf(fmaxf(sred[0], sred[1]), fmaxf(sred[2], sred[3]));

    int r0 = blockIdx.x * 8 + wv * 2;   // rows r0, r0+1
    float f1 = f1b[r0];
    float vv = f1 + mb, mm = fmaxf(vv, ALPHA * vv);
    float q1p0 = __builtin_amdgcn_exp2f(f1 - mm);
    float q1n0 = __builtin_amdgcn_exp2f(ALPHA * f1 - mm);
    f1 = f1b[r0 + 1];
    vv = f1 + mb; mm = fmaxf(vv, ALPHA * vv);
    float q1p1 = __builtin_amdgcn_exp2f(f1 - mm);
    float q1n1 = __builtin_amdgcn_exp2f(ALPHA * f1 - mm);

    float a00 = 0.f, a10 = 0.f, d0 = 0.f;
    float a01 = 0.f, a11 = 0.f, d1 = 0.f;
#pragma unroll 4
    for (int s = 0; s < N / 64; s++) {   // 128
        float4 q = rec2[s * 64 + lane];
        ull mw0 = maskT[(size_t)s * N + r0];
        ull mw1 = maskT[(size_t)s * N + r0 + 1];
        float w0 = fmaxf(q1p0 * q.x, q1n0 * q.w);
        w0 = ((mw0 >> lane) & 1ull) ? w0 : 0.f;
        float w1 = fmaxf(q1p1 * q.x, q1n1 * q.w);
        w1 = ((mw1 >> lane) & 1ull) ? w1 : 0.f;
        a00 = fmaf(w0, q.y, a00);
        a10 = fmaf(w0, q.z, a10);
        d0 += w0;
        a01 = fmaf(w1, q.y, a01);
        a11 = fmaf(w1, q.z, a11);
        d1 += w1;
    }
    for (int off = 32; off > 0; off >>= 1) {
        a00 += __shfl_xor(a00, off, 64);
        a10 += __shfl_xor(a10, off, 64);
        d0  += __shfl_xor(d0,  off, 64);
        a01 += __shfl_xor(a01, off, 64);
        a11 += __shfl_xor(a11, off, 64);
        d1  += __shfl_xor(d1,  off, 64);
    }
    if (lane == 0) {
#pragma unroll
        for (int i = 0; i < 2; i++) {
            float s0 = i ? a01 : a00;
            float s1 = i ? a11 : a10;
            float dd = i ? d1 : d0;
            float iv = 1.f / dd;
            float e0 = s0 * iv, e1 = s1 * iv;
            e0 = (e0 > 0.f) ? e0 : expm1f(e0);
            e1 = (e1 > 0.f) ? e1 : expm1f(e1);
            float mx = fmaxf(e0, e1);
            float lse = mx + logf(expf(e0 - mx) + expf(e1 - mx));
            ((float2*)out)[r0 + i] = make_float2(e0 - lse, e1 - lse);
        }
    }
}

extern "C" void kernel_launch(void* const* d_in, const int* in_sizes, int n_in,
                              void* d_out, int out_size, void* d_ws, size_t ws_size,
                              hipStream_t stream) {
    const float* x   = (const float*)d_in[0];
    const int*   adj = (const int*)d_in[1];
    const float* Wh  = (const float*)d_in[2];
    const float* ah  = (const float*)d_in[3];
    const float* Wo  = (const float*)d_in[4];
    const float* ao  = (const float*)d_in[5];
    float* out = (float*)d_out;
    float* ws = (float*)d_ws;

    // workspace layout (float offsets)
    ull*    maskT = (ull*)ws;                    // 8 MB word-transposed bitmask
    float*  e2p   = ws + 2097152;                // 4*N
    float*  e2n   = ws + 2129920;                // 4*N
    u16*    Bpk   = (u16*)(ws + 2162688);        // 1 MB
    float*  f1a   = ws + 2424832;                // 4*N
    float*  part1 = ws + 2457600;                // 8*36*N = 2359296
    float4* rec2  = (float4*)(ws + 4816896);     // N float4
    float*  f1b   = ws + 4849664;                // N
    float*  bmax1 = ws + 4857856;                // 4*512
    float*  bmax2 = ws + 4859904;                // 128

    kPack<<<N, 256, 0, stream>>>(adj, maskT);
    kFeat<<<N / 64, 256, 0, stream>>>(x, Wh, ah, e2p, e2n, Bpk, f1a, bmax1);
    kB_attn1<<<(N / 128) * JS * NH, 256, 0, stream>>>(maskT, e2p, e2n,
                                                      (const uint4*)Bpk, f1a,
                                                      bmax1, part1);
    kC_final1<<<N / 64, 64, 0, stream>>>(part1, Wo, ao, rec2, f1b, bmax2);
    kD_attn2<<<N / 8, 256, 0, stream>>>(maskT, rec2, f1b, bmax2, out);
}

// Round 7
// 506.091 us; speedup vs baseline: 1.5139x; 1.0561x over previous
//
#include <hip/hip_runtime.h>
#include <math.h>

#define N 8192
#define FIN 29
#define FH 8
#define NH 4
#define ALPHA 0.2f
#define LOG2E 1.4426950408889634f
#define JS 8            // layer-1 j-splits (8 -> 2048 blocks)
#define JRR (N / JS)    // 1024

typedef unsigned long long ull;
typedef unsigned short u16;
typedef __attribute__((ext_vector_type(8))) short bf16x8;
typedef __attribute__((ext_vector_type(4))) float f32x4;
typedef __attribute__((ext_vector_type(2))) float f32x2;

__device__ inline unsigned bf16rn(float f) {
    unsigned u = __float_as_uint(f);
    return (u + 0x7fffu + ((u >> 16) & 1u)) >> 16;
}
// packed f32 pair multiply (VOP3P) — one instruction, two products
__device__ inline f32x2 pk_mul(f32x2 a, f32x2 b) {
    f32x2 d;
    asm("v_pk_mul_f32 %0, %1, %2" : "=v"(d) : "v"(a), "v"(b));
    return d;
}

// w_ij = exp2(lrelu(f1+f2) - m) = max(E1p_i*E2p_j, E1n_i*E2n_j)  (exp2 monotone)
#define WTILE(E1P2, E1N2, SW, BP, ACC)                                          \
    {                                                                           \
        f32x2 wp, wn;                                                           \
        float w0, w1, w2, w3, w4, w5, w6, w7;                                   \
        wp = pk_mul(E1P2, p01); wn = pk_mul(E1N2, n01);                         \
        w0 = fmaxf(wp[0], wn[0]); w1 = fmaxf(wp[1], wn[1]);                     \
        wp = pk_mul(E1P2, p23); wn = pk_mul(E1N2, n23);                         \
        w2 = fmaxf(wp[0], wn[0]); w3 = fmaxf(wp[1], wn[1]);                     \
        wp = pk_mul(E1P2, p45); wn = pk_mul(E1N2, n45);                         \
        w4 = fmaxf(wp[0], wn[0]); w5 = fmaxf(wp[1], wn[1]);                     \
        wp = pk_mul(E1P2, p67); wn = pk_mul(E1N2, n67);                         \
        w6 = fmaxf(wp[0], wn[0]); w7 = fmaxf(wp[1], wn[1]);                     \
        w0 = (SW & 1u)   ? w0 : 0.f;                                            \
        w1 = (SW & 2u)   ? w1 : 0.f;                                            \
        w2 = (SW & 4u)   ? w2 : 0.f;                                            \
        w3 = (SW & 8u)   ? w3 : 0.f;                                            \
        w4 = (SW & 16u)  ? w4 : 0.f;                                            \
        w5 = (SW & 32u)  ? w5 : 0.f;                                            \
        w6 = (SW & 64u)  ? w6 : 0.f;                                            \
        w7 = (SW & 128u) ? w7 : 0.f;                                            \
        uint4 ap;                                                               \
        asm("v_cvt_pk_bf16_f32 %0, %1, %2" : "=v"(ap.x) : "v"(w0), "v"(w1));    \
        asm("v_cvt_pk_bf16_f32 %0, %1, %2" : "=v"(ap.y) : "v"(w2), "v"(w3));    \
        asm("v_cvt_pk_bf16_f32 %0, %1, %2" : "=v"(ap.z) : "v"(w4), "v"(w5));    \
        asm("v_cvt_pk_bf16_f32 %0, %1, %2" : "=v"(ap.w) : "v"(w6), "v"(w7));    \
        ACC = __builtin_amdgcn_mfma_f32_16x16x32_bf16(                          \
            __builtin_bit_cast(bf16x8, ap), __builtin_bit_cast(bf16x8, BP),     \
            ACC, 0, 0, 0);                                                      \
    }

// ============ kPF: fused adj-pack (blocks 0..8191) + features (blocks 8192..8319) ============
// Pack: ONE row per block, int4 (16B/lane) streaming loads -> ~6 TB/s regime.
// Word assembly in registers: lane holds 4-bit nibble for its 4 cols, 4-round
// shfl_xor OR-reduce within 16-lane groups builds each 64-bit word; 4 lanes
// store per wave-iter. NO load->ballot->store serialization.
// word w covers cols w*64+bit  (identical layout to previous maskT). 
__global__ __launch_bounds__(256) void kPF(
    const int* __restrict__ adj, const float* __restrict__ x,
    const float* __restrict__ Wh, const float* __restrict__ ah,
    ull* __restrict__ maskT, float* __restrict__ e2p, float* __restrict__ e2n,
    u16* __restrict__ Bpk, float* __restrict__ f1a, float* __restrict__ bmax1) {
    const int tid = threadIdx.x;
    const int blk = blockIdx.x;
    const int lane = tid & 63;
    const int wv = tid >> 6;

    if (blk < N) {
        // ---------------- pack path ----------------
        int row = blk;
        const int4* rp4 = (const int4*)(adj + (size_t)row * N);
        int sub = (lane & 15) * 4;          // bit offset within the 64-bit word
        int g = lane >> 4;                  // word group 0..3
#pragma unroll
        for (int i = 0; i < 8; i++) {
            int4 a = rp4[i * 256 + wv * 64 + lane];   // cols i*1024+wv*256+lane*4+..
            unsigned n = (unsigned)(a.x > 0) | ((unsigned)(a.y > 0) << 1) |
                         ((unsigned)(a.z > 0) << 2) | ((unsigned)(a.w > 0) << 3);
            ull t = (ull)n << sub;
            t |= __shfl_xor(t, 1, 64);
            t |= __shfl_xor(t, 2, 64);
            t |= __shfl_xor(t, 4, 64);
            t |= __shfl_xor(t, 8, 64);
            if ((lane & 15) == 0) {
                int wglob = i * 16 + wv * 4 + g;
                maskT[(size_t)wglob * N + row] = t;
            }
        }
        return;
    }
    // ---------------- feature path (128 blocks) ----------------
    __shared__ float sx[64 * FIN];
    __shared__ float sW[NH * FIN * FH];
    __shared__ float sa[NH * 2 * FH];
    int fb = blk - N;                       // 0..127
    for (int i = tid; i < NH * FIN * FH; i += 256) sW[i] = Wh[i];
    for (int i = tid; i < NH * 2 * FH; i += 256) sa[i] = ah[i];
    for (int i = tid; i < 64 * FIN; i += 256) sx[i] = x[(size_t)fb * 64 * FIN + i];
    __syncthreads();
    int h = tid & 3;
    int nl = tid >> 2;                      // node-local 0..63
    int node = fb * 64 + nl;
    float hv[FH];
#pragma unroll
    for (int k = 0; k < FH; k++) {
        float s = 0.f;
#pragma unroll
        for (int f = 0; f < FIN; f++) s += sx[nl * FIN + f] * sW[(h * FIN + f) * FH + k];
        hv[k] = s;
    }
    float f1 = 0.f, f2 = 0.f;
#pragma unroll
    for (int k = 0; k < FH; k++) {
        f1 += hv[k] * sa[h * 16 + k];
        f2 += hv[k] * sa[h * 16 + 8 + k];
    }
    float f1L = f1 * LOG2E, f2L = f2 * LOG2E;
    f1a[node * 4 + h] = f1L;
    e2p[(size_t)h * N + node] = __builtin_amdgcn_exp2f(f2L);
    e2n[(size_t)h * N + node] = __builtin_amdgcn_exp2f(ALPHA * f2L);
    // MFMA-fragment-order pack (JS=8 decomposition; c=8 -> ones column)
    int js = (node >> 10) & 7;
    int t  = (node >> 6) & 15;
    int hfl = (node >> 5) & 1;
    int kb = (node >> 3) & 3;
    int e  = node & 7;
    u16* dst = Bpk + ((size_t)(((h * 8 + js) * 16 + t) * 2 + hfl)) * 512 + e;
#pragma unroll
    for (int cc = 0; cc < 16; cc++) {
        u16 vv = (cc < FH) ? (u16)bf16rn(hv[cc])
                           : ((cc == 8) ? (u16)0x3F80u : (u16)0);
        dst[(kb * 16 + cc) * 8] = vv;
    }
    // per-head max over this wave's 16 nodes (head classes = lane mod 4)
    float v = f2L;
    for (int off = 4; off < 64; off <<= 1) v = fmaxf(v, __shfl_xor(v, off, 64));
    if ((tid & 63) < 4) bmax1[(tid & 3) * 512 + fb * 4 + wv] = v;
}

// ============ kB: layer-1 attention via MFMA, software-prefetched ============
// Grid 2048; LDS-staged e2 slabs; next-t mask words + Bpk fragments prefetched
// so each iteration's VMEM latency hides under the previous MFMA+VALU work.
__global__ __launch_bounds__(256, 4) void kB_attn1(
    const ull* __restrict__ maskT, const float* __restrict__ e2p,
    const float* __restrict__ e2n, const uint4* __restrict__ Bpk,
    const float* __restrict__ f1a, const float* __restrict__ bmax1,
    float* __restrict__ part1) {
    __shared__ __align__(16) float sE2p[JRR];   // 4 KB
    __shared__ __align__(16) float sE2n[JRR];   // 4 KB
    __shared__ float sred[4];
    int tid = threadIdx.x;
    int lane = tid & 63;
    int wv = tid >> 6;
    int h = blockIdx.x & 3;
    int js = (blockIdx.x >> 2) & 7;
    int rowblk = blockIdx.x >> 5;        // 0..63
    int jbase = js * JRR;

    // stage e2 slabs for this (head, j-range)
#pragma unroll
    for (int i = 0; i < JRR / 256; i++) {   // 4
        sE2p[tid + i * 256] = e2p[(size_t)h * N + jbase + tid + i * 256];
        sE2n[tid + i * 256] = e2n[(size_t)h * N + jbase + tid + i * 256];
    }
    // mfL = global max of f2L for this head
    float v = -3.0e38f;
    for (int i = tid; i < 512; i += 256) v = fmaxf(v, bmax1[h * 512 + i]);
    for (int off = 32; off > 0; off >>= 1) v = fmaxf(v, __shfl_xor(v, off, 64));
    if (lane == 0) sred[wv] = v;
    __syncthreads();
    float mfL = fmaxf(fmaxf(sred[0], sred[1]), fmaxf(sred[2], sred[3]));

    int c = lane & 15;                   // B col / A row selector
    int kb = lane >> 4;                  // k-group 0..3
    int sh = kb * 8;
    int r0 = rowblk * 128 + wv * 16 + c;
    int r1 = r0 + 64;

    float f1 = f1a[r0 * 4 + h];
    float vv = f1 + mfL, mm = fmaxf(vv, ALPHA * vv);
    f32x2 e1p0, e1n0, e1p1, e1n1;
    e1p0[0] = e1p0[1] = __builtin_amdgcn_exp2f(f1 - mm);
    e1n0[0] = e1n0[1] = __builtin_amdgcn_exp2f(ALPHA * f1 - mm);
    f1 = f1a[r1 * 4 + h];
    vv = f1 + mfL; mm = fmaxf(vv, ALPHA * vv);
    e1p1[0] = e1p1[1] = __builtin_amdgcn_exp2f(f1 - mm);
    e1n1[0] = e1n1[1] = __builtin_amdgcn_exp2f(ALPHA * f1 - mm);

    const ull* mrow0 = maskT + (size_t)(js * (JRR / 64)) * N + r0;
    const ull* mrow1 = maskT + (size_t)(js * (JRR / 64)) * N + r1;
    const uint4* bp0 = Bpk + (size_t)(h * 8 + js) * 2048 + lane;
    const float* pph = sE2p + kb * 8;
    const float* nnh = sE2n + kb * 8;

    f32x4 acc0 = {0.f, 0.f, 0.f, 0.f};
    f32x4 acc1 = {0.f, 0.f, 0.f, 0.f};

    // prefetch t=0
    ull mw0 = mrow0[0];
    ull mw1 = mrow1[0];
    uint4 bpA = bp0[0];
    uint4 bpB = bp0[64];

    for (int t = 0; t < JRR / 64; t++) {   // 16
        ull nmw0 = mw0, nmw1 = mw1;
        uint4 nbpA = bpA, nbpB = bpB;
        if (t < JRR / 64 - 1) {            // issue next-t loads early
            nmw0 = mrow0[(size_t)(t + 1) * N];
            nmw1 = mrow1[(size_t)(t + 1) * N];
            nbpA = bp0[(t + 1) * 128];
            nbpB = bp0[(t + 1) * 128 + 64];
        }
#pragma unroll
        for (int hf = 0; hf < 2; hf++) {
            f32x4 P0 = *(const f32x4*)(pph + t * 64 + hf * 32);
            f32x4 P1 = *(const f32x4*)(pph + t * 64 + hf * 32 + 4);
            f32x4 Q0 = *(const f32x4*)(nnh + t * 64 + hf * 32);
            f32x4 Q1 = *(const f32x4*)(nnh + t * 64 + hf * 32 + 4);
            f32x2 p01 = __builtin_shufflevector(P0, P0, 0, 1);
            f32x2 p23 = __builtin_shufflevector(P0, P0, 2, 3);
            f32x2 p45 = __builtin_shufflevector(P1, P1, 0, 1);
            f32x2 p67 = __builtin_shufflevector(P1, P1, 2, 3);
            f32x2 n01 = __builtin_shufflevector(Q0, Q0, 0, 1);
            f32x2 n23 = __builtin_shufflevector(Q0, Q0, 2, 3);
            f32x2 n45 = __builtin_shufflevector(Q1, Q1, 0, 1);
            f32x2 n67 = __builtin_shufflevector(Q1, Q1, 2, 3);
            uint4 bp = hf ? bpB : bpA;
            unsigned sw0 = ((unsigned)(mw0 >> (hf * 32))) >> sh;
            unsigned sw1 = ((unsigned)(mw1 >> (hf * 32))) >> sh;
            WTILE(e1p0, e1n0, sw0, bp, acc0)
            WTILE(e1p1, e1n1, sw1, bp, acc1)
        }
        mw0 = nmw0; mw1 = nmw1; bpA = nbpA; bpB = nbpB;
    }
    if (c <= 8) {   // cols 0..7 = features, 8 = denominator
        int ro = rowblk * 128 + wv * 16 + kb * 4;
        float* dstp = part1 + (size_t)(js * 36 + h * 9 + c) * N + ro;
        *(float4*)dstp = make_float4(acc0[0], acc0[1], acc0[2], acc0[3]);
        *(float4*)(dstp + 64) = make_float4(acc1[0], acc1[1], acc1[2], acc1[3]);
    }
}

// ============ kC: finalize layer 1 + layer-2 features + bmax2 ============
__global__ __launch_bounds__(64) void kC_final1(
    const float* __restrict__ part1, const float* __restrict__ Wo,
    const float* __restrict__ ao,
    float4* __restrict__ rec2, float* __restrict__ f1b,
    float* __restrict__ bmax2) {
    __shared__ float sW[64];
    __shared__ float sa[4];
    int tid = threadIdx.x;
    sW[tid] = Wo[tid];
    if (tid < 4) sa[tid] = ao[tid];
    __syncthreads();
    int row = blockIdx.x * 64 + tid;
    float hv[32];
#pragma unroll
    for (int h = 0; h < NH; h++) {
        float s[9];
#pragma unroll
        for (int cc = 0; cc < 9; cc++) {
            float acc = 0.f;
#pragma unroll
            for (int js = 0; js < JS; js++)
                acc += part1[(size_t)(js * 36 + h * 9 + cc) * N + row];
            s[cc] = acc;
        }
        float inv = 1.f / s[8];
#pragma unroll
        for (int k = 0; k < FH; k++) {
            float o = s[k] * inv;
            hv[h * 8 + k] = (o > 0.f) ? o : expm1f(o);
        }
    }
    float h0 = 0.f, h1 = 0.f;
#pragma unroll
    for (int i = 0; i < 32; i++) {
        h0 = fmaf(hv[i], sW[i * 2 + 0], h0);
        h1 = fmaf(hv[i], sW[i * 2 + 1], h1);
    }
    float f1 = (h0 * sa[0] + h1 * sa[1]) * LOG2E;
    float f2 = (h0 * sa[2] + h1 * sa[3]) * LOG2E;
    rec2[row] = make_float4(__builtin_amdgcn_exp2f(f2), h0, h1,
                            __builtin_amdgcn_exp2f(ALPHA * f2));
    f1b[row] = f1;
    float vmax = f2;
    for (int off = 32; off > 0; off >>= 1) vmax = fmaxf(vmax, __shfl_xor(vmax, off, 64));
    if (tid == 0) bmax2[blockIdx.x] = vmax;
}

// ============ kD: layer-2 attention + log_softmax (fused) ============
__global__ __launch_bounds__(256) void kD_attn2(
    const ull* __restrict__ maskT, const float4* __restrict__ rec2,
    const float* __restrict__ f1b, const float* __restrict__ bmax2,
    float* __restrict__ out) {
    __shared__ float sred[4];
    int tid = threadIdx.x;
    int lane = tid & 63;
    int wv = tid >> 6;

    // mb = global max of layer-2 f2 (reduce bmax2[0..127])
    float v = (tid < 128) ? bmax2[tid] : -3.0e38f;
    for (int off = 32; off > 0; off >>= 1) v = fmaxf(v, __shfl_xor(v, off, 64));
    if (lane == 0) sred[wv] = v;
    __syncthreads();
    float mb = fmaxf(fmaxf(sred[0], sred[1]), fmaxf(sred[2], sred[3]));

    int r0 = blockIdx.x * 8 + wv * 2;   // rows r0, r0+1
    float f1 = f1b[r0];
    float vv = f1 + mb, mm = fmaxf(vv, ALPHA * vv);
    float q1p0 = __builtin_amdgcn_exp2f(f1 - mm);
    float q1n0 = __builtin_amdgcn_exp2f(ALPHA * f1 - mm);
    f1 = f1b[r0 + 1];
    vv = f1 + mb; mm = fmaxf(vv, ALPHA * vv);
    float q1p1 = __builtin_amdgcn_exp2f(f1 - mm);
    float q1n1 = __builtin_amdgcn_exp2f(ALPHA * f1 - mm);

    float a00 = 0.f, a10 = 0.f, d0 = 0.f;
    float a01 = 0.f, a11 = 0.f, d1 = 0.f;
#pragma unroll 4
    for (int s = 0; s < N / 64; s++) {   // 128
        float4 q = rec2[s * 64 + lane];
        ull mw0 = maskT[(size_t)s * N + r0];
        ull mw1 = maskT[(size_t)s * N + r0 + 1];
        float w0 = fmaxf(q1p0 * q.x, q1n0 * q.w);
        w0 = ((mw0 >> lane) & 1ull) ? w0 : 0.f;
        float w1 = fmaxf(q1p1 * q.x, q1n1 * q.w);
        w1 = ((mw1 >> lane) & 1ull) ? w1 : 0.f;
        a00 = fmaf(w0, q.y, a00);
        a10 = fmaf(w0, q.z, a10);
        d0 += w0;
        a01 = fmaf(w1, q.y, a01);
        a11 = fmaf(w1, q.z, a11);
        d1 += w1;
    }
    for (int off = 32; off > 0; off >>= 1) {
        a00 += __shfl_xor(a00, off, 64);
        a10 += __shfl_xor(a10, off, 64);
        d0  += __shfl_xor(d0,  off, 64);
        a01 += __shfl_xor(a01, off, 64);
        a11 += __shfl_xor(a11, off, 64);
        d1  += __shfl_xor(d1,  off, 64);
    }
    if (lane == 0) {
#pragma unroll
        for (int i = 0; i < 2; i++) {
            float s0 = i ? a01 : a00;
            float s1 = i ? a11 : a10;
            float dd = i ? d1 : d0;
            float iv = 1.f / dd;
            float e0 = s0 * iv, e1 = s1 * iv;
            e0 = (e0 > 0.f) ? e0 : expm1f(e0);
            e1 = (e1 > 0.f) ? e1 : expm1f(e1);
            float mx = fmaxf(e0, e1);
            float lse = mx + logf(expf(e0 - mx) + expf(e1 - mx));
            ((float2*)out)[r0 + i] = make_float2(e0 - lse, e1 - lse);
        }
    }
}

extern "C" void kernel_launch(void* const* d_in, const int* in_sizes, int n_in,
                              void* d_out, int out_size, void* d_ws, size_t ws_size,
                              hipStream_t stream) {
    const float* x   = (const float*)d_in[0];
    const int*   adj = (const int*)d_in[1];
    const float* Wh  = (const float*)d_in[2];
    const float* ah  = (const float*)d_in[3];
    const float* Wo  = (const float*)d_in[4];
    const float* ao  = (const float*)d_in[5];
    float* out = (float*)d_out;
    float* ws = (float*)d_ws;

    // workspace layout (float offsets)
    ull*    maskT = (ull*)ws;                    // 8 MB word-transposed bitmask
    float*  e2p   = ws + 2097152;                // 4*N
    float*  e2n   = ws + 2129920;                // 4*N
    u16*    Bpk   = (u16*)(ws + 2162688);        // 1 MB
    float*  f1a   = ws + 2424832;                // 4*N
    float*  part1 = ws + 2457600;                // 8*36*N = 2359296
    float4* rec2  = (float4*)(ws + 4816896);     // N float4
    float*  f1b   = ws + 4849664;                // N
    float*  bmax1 = ws + 4857856;                // 4*512
    float*  bmax2 = ws + 4859904;                // 128

    kPF<<<N + 128, 256, 0, stream>>>(adj, x, Wh, ah, maskT, e2p, e2n, Bpk,
                                     f1a, bmax1);
    kB_attn1<<<(N / 128) * JS * NH, 256, 0, stream>>>(maskT, e2p, e2n,
                                                      (const uint4*)Bpk, f1a,
                                                      bmax1, part1);
    kC_final1<<<N / 64, 64, 0, stream>>>(part1, Wo, ao, rec2, f1b, bmax2);
    kD_attn2<<<N / 8, 256, 0, stream>>>(maskT, rec2, f1b, bmax2, out);
}